// Round 11
// baseline (161.426 us; speedup 1.0000x reference)
//
#include <hip/hip_runtime.h>
#include <math.h>

#define N_B 16
#define C_CH 128
#define T_LEN 513
#define NI 257
#define NJ 256
#define NTOT (C_CH*T_LEN)              // 65,664 floats per batch
#define NQ4  (NTOT/4)                  // 16,416 float4 per batch
#define SCALE (1.4426950408889634f/128.0f)     // log2(e)/C

typedef unsigned u32;
typedef unsigned short u16;
typedef short bf16x8 __attribute__((ext_vector_type(8)));
typedef float f32x4 __attribute__((ext_vector_type(4)));

// workspace: RAM f32[16][257][256] ; pda f32[16][17][256] ; counters u32[16]
#define RAM_F 0
#define PDA_F (N_B*NI*NJ)
#define CNT_BYTE ((PDA_F + N_B*17*NJ) * 4)

__device__ inline u16 bf16_rne(float f) {
    const u32 u = __builtin_bit_cast(u32, f);
    return (u16)((u + 0x7fffu + ((u >> 16) & 1u)) >> 16);
}
__device__ inline float bl2f(u16 h) {
    return __builtin_bit_cast(float, (u32)h << 16);
}
__device__ inline void cvt8(const float* fa, bf16x8& hv, bf16x8& lv) {
    union { u32 w[4]; bf16x8 v; } H, L;
    #pragma unroll
    for (int p = 0; p < 4; ++p) {
        const float a = fa[2*p], b = fa[2*p+1];
        const u16 ha = bf16_rne(a), hb = bf16_rne(b);
        const u16 la = bf16_rne(a - bl2f(ha)), lb = bf16_rne(b - bl2f(hb));
        H.w[p] = (u32)ha | ((u32)hb << 16);
        L.w[p] = (u32)la | ((u32)lb << 16);
    }
    hv = H.v; lv = L.v;
}
// exact e/513 for e < 65,664 (513*33489024 = 2^34+128)
__device__ inline u32 div513(u32 e) {
    return (u32)(((unsigned long long)e * 33489024ull) >> 34);
}

// grid = 544 blocks (34 per batch: 2 jh x 17 ib), 512 threads.
// Tile work identical to R10-k1 (proven). Last block per batch runs the epilogue.
__global__ __launch_bounds__(512, 4) void k_all(const float* __restrict__ x,
                                                float* __restrict__ ws,
                                                float* __restrict__ out) {
    __shared__ float Bs[128][132];
    __shared__ float As[16][132];
    __shared__ float w_s[NJ];
    __shared__ float f_s[260];
    __shared__ int lastFlag;

    float* ram = ws + RAM_F;
    float* pda = ws + PDA_F;
    u32* cnt = (u32*)((char*)ws + CNT_BYTE);

    const int bid = blockIdx.x;
    const int n = bid / 34, rem = bid % 34;
    const int jh = rem & 1, ib = rem >> 1;
    const int i0 = ib * 16, T0 = jh * 256;
    const int tid = threadIdx.x;
    const float* xn = x + (size_t)n * NTOT;
    float* rn = ram + (size_t)n * NI * NJ;

    // ---------------- Phase 1: stage + MFMA tile + RAM + pda (R10-proven) ----------------
    {   // stage A: even t = 2*i0 .. 2*i0+30 (zero-pad t>512)
        const int c = tid >> 2, k = tid & 3;
        #pragma unroll
        for (int m = 0; m < 4; ++m) {
            const int t = 2 * i0 + 8 * k + 2 * m;
            As[4 * k + m][c] = (t <= 512) ? xn[c * T_LEN + t] : 0.f;
        }
    }
    {   // stage B: contiguous t-window [T0, T0+256); odd lanes keep odd t
        const int w = tid >> 6, l = tid & 63;
        #pragma unroll
        for (int cc = 0; cc < 16; ++cc) {
            const int c = w * 16 + cc;
            #pragma unroll
            for (int p = 0; p < 4; ++p) {
                const int toff = p * 64 + l;
                const float f = xn[c * T_LEN + T0 + toff];
                if (toff & 1) Bs[toff >> 1][c] = f;
            }
        }
    }
    __syncthreads();

    const int l = tid & 63, wv = tid >> 6;
    const int il = l & 15, g = l >> 4;
    {
        bf16x8 ah[4], al[4], bh[4], bl[4];
        float psum = 0.f, qsq = 0.f;
        #pragma unroll
        for (int kc = 0; kc < 4; ++kc) {
            float fa[8], fb[8];
            const float* ap = &As[il][kc * 32 + 8 * g];
            const float* bp = &Bs[wv * 16 + il][kc * 32 + 8 * g];
            #pragma unroll
            for (int e = 0; e < 8; ++e) { fa[e] = ap[e]; fb[e] = bp[e]; }
            #pragma unroll
            for (int e = 0; e < 8; ++e) {
                psum = fmaf(fa[e], fa[e], psum);
                qsq  = fmaf(fb[e], fb[e], qsq);
            }
            cvt8(fa, ah[kc], al[kc]);
            cvt8(fb, bh[kc], bl[kc]);
        }
        psum += __shfl_xor(psum, 16, 64);
        psum += __shfl_xor(psum, 32, 64);         // P[i0+il] replicated
        qsq  += __shfl_xor(qsq, 16, 64);
        qsq  += __shfl_xor(qsq, 32, 64);          // Q[j] replicated
        float pv[4];
        #pragma unroll
        for (int r = 0; r < 4; ++r) pv[r] = __shfl(psum, 4 * g + r, 64);

        f32x4 acc = {0.f, 0.f, 0.f, 0.f};
        #pragma unroll
        for (int kc = 0; kc < 4; ++kc) {
            acc = __builtin_amdgcn_mfma_f32_16x16x32_bf16(ah[kc], bh[kc], acc, 0, 0, 0);
            acc = __builtin_amdgcn_mfma_f32_16x16x32_bf16(ah[kc], bl[kc], acc, 0, 0, 0);
            acc = __builtin_amdgcn_mfma_f32_16x16x32_bf16(al[kc], bh[kc], acc, 0, 0, 0);
        }
        const int j0 = jh * 128 + wv * 16;
        float cs = 0.f;
        #pragma unroll
        for (int r = 0; r < 4; ++r) {
            const int i = i0 + 4 * g + r;
            const float rv = exp2f((pv[r] + qsq - 2.f * acc[r]) * SCALE);
            if (i < NI) { rn[(size_t)i * NJ + j0 + il] = rv; cs += rv; }  // RAM>=1: 0.5-thr dead
        }
        cs += __shfl_xor(cs, 16, 64);
        cs += __shfl_xor(cs, 32, 64);
        if (l < 16) pda[((size_t)n * 17 + ib) * NJ + j0 + l] = cs;
    }

    // ---------------- election: last of the 34 blocks for this batch -------------------
    __threadfence();                               // release: flush this block's writes
    __syncthreads();
    if (tid == 0) {
        const u32 old = atomicAdd(&cnt[n], 1u);
        lastFlag = (old == 33u);
    }
    __syncthreads();
    if (!lastFlag) return;
    __threadfence();                               // acquire: invalidate before reads

    // ---------------- Phase 2 (one block per batch): w, row reduce, apply --------------
    if (tid < NJ) {
        float da = 0.f;
        #pragma unroll
        for (int k = 0; k < 17; ++k) da += pda[((size_t)n * 17 + k) * NJ + tid];
        w_s[tid] = rsqrtf(da);                     // da >= 257, eps negligible
    }
    __syncthreads();
    {
        const float4 w4 = *(const float4*)&w_s[4 * l];
        for (int i = wv; i < NI; i += 8) {
            const float4 v = *(const float4*)&rn[(size_t)i * NJ + 4 * l];
            float t0 = v.x * w4.x + v.y * w4.y + v.z * w4.z + v.w * w4.w;
            float db = v.x + v.y + v.z + v.w;
            #pragma unroll
            for (int o = 32; o; o >>= 1) {
                t0 += __shfl_xor(t0, o, 64);
                db += __shfl_xor(db, o, 64);
            }
            if (l == 0) f_s[i] = 2.f * t0 * rsqrtf(db);
        }
    }
    __syncthreads();
    {   // fused apply: out = x * f_s[t>>1], coalesced float4 sweep
        float* on = out + (size_t)n * NTOT;
        for (int it = 0; it < 33; ++it) {
            const int q = it * 512 + tid;
            if (q < NQ4) {
                const float4 v = *(const float4*)(xn + 4 * (size_t)q);
                const u32 e = 4 * (u32)q;
                const u32 c = div513(e);
                int t = (int)(e - 513u * c);
                const float vv[4] = {v.x, v.y, v.z, v.w};
                float ov[4];
                #pragma unroll
                for (int k = 0; k < 4; ++k) {
                    int tk = t + k;
                    if (tk >= 513) tk -= 513;
                    ov[k] = vv[k] * f_s[tk >> 1];
                }
                float4 o4; o4.x = ov[0]; o4.y = ov[1]; o4.z = ov[2]; o4.w = ov[3];
                *(float4*)(on + 4 * (size_t)q) = o4;
            }
        }
    }
}

extern "C" void kernel_launch(void* const* d_in, const int* in_sizes, int n_in,
                              void* d_out, int out_size, void* d_ws, size_t ws_size,
                              hipStream_t stream) {
    const float* x = (const float*)d_in[0];
    float* out = (float*)d_out;
    float* ws = (float*)d_ws;
    hipMemsetAsync((char*)d_ws + CNT_BYTE, 0, 64, stream);   // reset per-batch counters
    k_all<<<544, 512, 0, stream>>>(x, ws, out);
}

// Round 12
// 22.916 us; speedup vs baseline: 7.0444x; 7.0444x over previous
//
#include <hip/hip_runtime.h>
#include <math.h>

#define N_B 16
#define C_CH 128
#define T_LEN 513
#define NI 257
#define NJ 256
#define SCALE (1.4426950408889634f/128.0f)     // log2(e)/C

typedef unsigned u32;
typedef unsigned short u16;
typedef short bf16x8 __attribute__((ext_vector_type(8)));
typedef float f32x4 __attribute__((ext_vector_type(4)));

// workspace: RAM f32[16][257][256] ; pda f32[16][17][256] (slot16 = row 256)
#define RAM_F 0
#define PDA_F (N_B*NI*NJ)

__device__ inline u16 bf16_rne(float f) {
    const u32 u = __builtin_bit_cast(u32, f);
    return (u16)((u + 0x7fffu + ((u >> 16) & 1u)) >> 16);
}
__device__ inline float bl2f(u16 h) {
    return __builtin_bit_cast(float, (u32)h << 16);
}
__device__ inline void cvt8(const float* fa, bf16x8& hv, bf16x8& lv) {
    union { u32 w[4]; bf16x8 v; } H, L;
    #pragma unroll
    for (int p = 0; p < 4; ++p) {
        const float a = fa[2*p], b = fa[2*p+1];
        const u16 ha = bf16_rne(a), hb = bf16_rne(b);
        const u16 la = bf16_rne(a - bl2f(ha)), lb = bf16_rne(b - bl2f(hb));
        H.w[p] = (u32)ha | ((u32)hb << 16);
        L.w[p] = (u32)la | ((u32)lb << 16);
    }
    hv = H.v; lv = L.v;
}

// ---------------- K1: grid (jq=4, ib=8, n=16) = 512 blocks x 512 thr, 50.7 KB LDS.
// Block = 32 i-rows x 64 j-cols. 8 waves: (ih,jt) -> one 16x16 tile each.
// ib==0 blocks additionally compute RAM row 256 (full fp32 GEMV vs staged Bs).
__global__ __launch_bounds__(512, 6) void k1(const float* __restrict__ x,
                                             float* __restrict__ ram,
                                             float* __restrict__ pda) {
    __shared__ float As[32][132];
    __shared__ float Bs[64][132];
    const int jq = blockIdx.x, ib = blockIdx.y, n = blockIdx.z;
    const int i0 = ib * 32, j0 = jq * 64;
    const int tid = threadIdx.x;
    const int l = tid & 63, wv = tid >> 6;
    const float* xn = x + (size_t)n * (C_CH * T_LEN);
    float* rn = ram + (size_t)n * NI * NJ;

    {   // stage A: contiguous even-t window [2*i0, 2*i0+64), wave w covers c=16w..16w+15
        #pragma unroll
        for (int cc = 0; cc < 16; ++cc) {
            const int c = wv * 16 + cc;
            const float f = xn[c * T_LEN + 2 * i0 + l];      // t <= 511 always
            if (!(l & 1)) As[l >> 1][c] = f;
        }
        // stage B: contiguous window [2*j0, 2*j0+128), keep odd t
        #pragma unroll
        for (int cc = 0; cc < 16; ++cc) {
            const int c = wv * 16 + cc;
            #pragma unroll
            for (int p = 0; p < 2; ++p) {
                const int toff = p * 64 + l;
                const float f = xn[c * T_LEN + 2 * j0 + toff];   // t <= 511 always
                if (toff & 1) Bs[toff >> 1][c] = f;
            }
        }
    }
    __syncthreads();

    const int il = l & 15, g = l >> 4;
    const int ih = wv >> 2, jt = wv & 3;
    {
        bf16x8 ah[4], al[4], bh[4], bl[4];
        float psum = 0.f, qsq = 0.f;
        #pragma unroll
        for (int kc = 0; kc < 4; ++kc) {
            float fa[8], fb[8];
            const float* ap = &As[ih * 16 + il][kc * 32 + 8 * g];
            const float* bp = &Bs[jt * 16 + il][kc * 32 + 8 * g];
            #pragma unroll
            for (int e = 0; e < 8; ++e) { fa[e] = ap[e]; fb[e] = bp[e]; }
            #pragma unroll
            for (int e = 0; e < 8; ++e) {
                psum = fmaf(fa[e], fa[e], psum);
                qsq  = fmaf(fb[e], fb[e], qsq);
            }
            cvt8(fa, ah[kc], al[kc]);
            cvt8(fb, bh[kc], bl[kc]);
        }
        psum += __shfl_xor(psum, 16, 64);
        psum += __shfl_xor(psum, 32, 64);         // P[row il] replicated
        qsq  += __shfl_xor(qsq, 16, 64);
        qsq  += __shfl_xor(qsq, 32, 64);          // Q[col il] replicated
        float pv[4];
        #pragma unroll
        for (int r = 0; r < 4; ++r) pv[r] = __shfl(psum, 4 * g + r, 64);

        f32x4 acc = {0.f, 0.f, 0.f, 0.f};
        #pragma unroll
        for (int kc = 0; kc < 4; ++kc) {
            acc = __builtin_amdgcn_mfma_f32_16x16x32_bf16(ah[kc], bh[kc], acc, 0, 0, 0);
            acc = __builtin_amdgcn_mfma_f32_16x16x32_bf16(ah[kc], bl[kc], acc, 0, 0, 0);
            acc = __builtin_amdgcn_mfma_f32_16x16x32_bf16(al[kc], bh[kc], acc, 0, 0, 0);
        }
        const int j = j0 + jt * 16 + il;
        float cs = 0.f;
        #pragma unroll
        for (int r = 0; r < 4; ++r) {
            const int i = i0 + ih * 16 + 4 * g + r;           // always < 256
            const float rv = exp2f((pv[r] + qsq - 2.f * acc[r]) * SCALE);
            rn[(size_t)i * NJ + j] = rv;          // RAM >= 1: 0.5-threshold dead
            cs += rv;
        }
        cs += __shfl_xor(cs, 16, 64);
        cs += __shfl_xor(cs, 32, 64);
        if (l < 16) pda[((size_t)n * 17 + ib * 2 + ih) * NJ + j0 + jt * 16 + l] = cs;
    }

    // ---- row 256 (t=512): only ib==0 blocks; reuse staged Bs; full fp32.
    if (ib == 0) {
        const int jl = tid >> 3, sub = tid & 7;   // 64 j-groups x 8 lanes
        float sab = 0.f, saa = 0.f, sbb = 0.f;
        #pragma unroll
        for (int e = 0; e < 16; ++e) {
            const int c = sub * 16 + e;
            const float a = xn[c * T_LEN + 512];
            const float b = Bs[jl][c];
            sab = fmaf(a, b, sab);
            saa = fmaf(a, a, saa);
            sbb = fmaf(b, b, sbb);
        }
        #pragma unroll
        for (int o = 4; o; o >>= 1) {
            sab += __shfl_xor(sab, o, 64);
            saa += __shfl_xor(saa, o, 64);
            sbb += __shfl_xor(sbb, o, 64);
        }
        if (sub == 0) {
            const float rv = exp2f((saa + sbb - 2.f * sab) * SCALE);
            rn[(size_t)256 * NJ + j0 + jl] = rv;
            pda[((size_t)n * 17 + 16) * NJ + j0 + jl] = rv;
        }
    }
}

// ---------------- K2: w_j=rsqrt(da); per-row db + weighted rowsum; fused apply. (R10-proven)
__global__ __launch_bounds__(256) void k2(const float* __restrict__ ram,
                                          const float* __restrict__ pda,
                                          const float* __restrict__ x,
                                          float* __restrict__ out) {
    const int ic = blockIdx.x, n = blockIdx.y;
    __shared__ float w_s[NJ];
    __shared__ float f_s[16];
    const int tid = threadIdx.x;
    {
        float da = 0.f;
        #pragma unroll
        for (int k = 0; k < 17; ++k) da += pda[((size_t)n * 17 + k) * NJ + tid];
        w_s[tid] = rsqrtf(da);                    // da >= 257, eps negligible
    }
    __syncthreads();
    const int wv = tid >> 6, lane = tid & 63;
    #pragma unroll
    for (int rr = 0; rr < 4; ++rr) {
        const int lr = wv * 4 + rr;
        const int i = ic * 16 + lr;
        if (i < NI) {
            const float* rrow = ram + ((size_t)n * NI + i) * NJ;
            float db = 0.f, t0 = 0.f;
            #pragma unroll
            for (int k = 0; k < 4; ++k) {
                const float v = rrow[lane + 64 * k];
                db += v;
                t0 = fmaf(v, w_s[lane + 64 * k], t0);
            }
            #pragma unroll
            for (int off = 32; off; off >>= 1) {
                db += __shfl_xor(db, off, 64);
                t0 += __shfl_xor(t0, off, 64);
            }
            if (lane == 0) f_s[lr] = 2.f * t0 * rsqrtf(db);
        }
    }
    __syncthreads();
    const int tt = tid & 31, cgp = tid >> 5;
    const int t = ic * 32 + tt;
    if (t < T_LEN) {
        const float f = f_s[tt >> 1];
        const float* xn = x + (size_t)n * C_CH * T_LEN;
        float* on = out + (size_t)n * C_CH * T_LEN;
        #pragma unroll
        for (int p = 0; p < 16; ++p) {
            const int c = cgp * 16 + p;
            on[c * T_LEN + t] = xn[c * T_LEN + t] * f;
        }
    }
}

extern "C" void kernel_launch(void* const* d_in, const int* in_sizes, int n_in,
                              void* d_out, int out_size, void* d_ws, size_t ws_size,
                              hipStream_t stream) {
    const float* x = (const float*)d_in[0];
    float* out = (float*)d_out;
    float* ws = (float*)d_ws;
    float* ram = ws + RAM_F;
    float* pda = ws + PDA_F;

    k1<<<dim3(4, 8, N_B), 512, 0, stream>>>(x, ram, pda);
    k2<<<dim3(17, N_B), 256, 0, stream>>>(ram, pda, x, out);
}

// Round 13
// 21.444 us; speedup vs baseline: 7.5277x; 1.0686x over previous
//
#include <hip/hip_runtime.h>
#include <math.h>

#define N_B 16
#define C_CH 128
#define T_LEN 513
#define NI 257
#define NJ 256
#define SCALE (1.4426950408889634f/128.0f)     // log2(e)/C

typedef unsigned u32;
typedef unsigned short u16;
typedef short bf16x8 __attribute__((ext_vector_type(8)));
typedef float f32x4 __attribute__((ext_vector_type(4)));

// workspace: RAM f32[16][257][256] ; pda f32[16][17][256] (slot16 = row 256)
#define RAM_F 0
#define PDA_F (N_B*NI*NJ)

__device__ inline u32 cvtpk(float a, float b) {   // packed bf16(a)|bf16(b)<<16
    u32 r;
    asm("v_cvt_pk_bf16_f32 %0, %1, %2" : "=v"(r) : "v"(a), "v"(b));
    return r;
}

// hi = rne(a,b) packed; lo = rne of exact residuals (compensates any hi rounding)
__device__ inline void cvt8(const float* fa, bf16x8& hv, bf16x8& lv) {
    union { u32 w[4]; bf16x8 v; } H, L;
    #pragma unroll
    for (int p = 0; p < 4; ++p) {
        const float a = fa[2*p], b = fa[2*p+1];
        const u32 h = cvtpk(a, b);
        const float la = a - __builtin_bit_cast(float, h << 16);
        const float lb = b - __builtin_bit_cast(float, h & 0xffff0000u);
        H.w[p] = h;
        L.w[p] = cvtpk(la, lb);
    }
    hv = H.v; lv = L.v;
}

// ---------------- K1: grid (jq=4, ib=8, n=16) = 512 blocks x 512 thr, 50.7 KB LDS.
// Block = 32 i-rows x 64 j-cols. 8 waves: (ih,jt) -> one 16x16 tile each.
// ib==0 blocks additionally compute RAM row 256 (full fp32 GEMV vs staged Bs).
__global__ __launch_bounds__(512, 4) void k1(const float* __restrict__ x,
                                             float* __restrict__ ram,
                                             float* __restrict__ pda) {
    __shared__ float As[32][132];
    __shared__ float Bs[64][132];
    const int jq = blockIdx.x, ib = blockIdx.y, n = blockIdx.z;
    const int i0 = ib * 32, j0 = jq * 64;
    const int tid = threadIdx.x;
    const int l = tid & 63, wv = tid >> 6;
    const float* xn = x + (size_t)n * (C_CH * T_LEN);
    float* rn = ram + (size_t)n * NI * NJ;

    {   // stage A: even t in [2*i0, 2*i0+64) -> As[e][c], 8 aligned float2/thread
        const int e = l & 31, chalf = l >> 5;
        #pragma unroll
        for (int m = 0; m < 8; ++m) {
            const int c = wv * 16 + 2 * m + chalf;
            const int idx = c * T_LEN + 2 * i0 + 2 * e;
            const float2 f2 = *(const float2*)(xn + (idx & ~1));
            As[e][c] = (idx & 1) ? f2.y : f2.x;
        }
        // stage B: odd t in [2*j0, 2*j0+128) -> Bs[o][c], 16 aligned float2/thread
        #pragma unroll
        for (int m = 0; m < 16; ++m) {
            const int c = wv * 16 + m;
            const int idx = c * T_LEN + 2 * j0 + 2 * l + 1;
            const float2 f2 = *(const float2*)(xn + (idx & ~1));
            Bs[l][c] = (idx & 1) ? f2.y : f2.x;
        }
    }
    __syncthreads();

    const int il = l & 15, g = l >> 4;
    const int ih = wv >> 2, jt = wv & 3;
    {
        bf16x8 ah[4], al[4], bh[4], bl[4];
        float psum = 0.f, qsq = 0.f;
        #pragma unroll
        for (int kc = 0; kc < 4; ++kc) {
            float fa[8], fb[8];
            const float* ap = &As[ih * 16 + il][kc * 32 + 8 * g];
            const float* bp = &Bs[jt * 16 + il][kc * 32 + 8 * g];
            #pragma unroll
            for (int e = 0; e < 8; ++e) { fa[e] = ap[e]; fb[e] = bp[e]; }
            #pragma unroll
            for (int e = 0; e < 8; ++e) {
                psum = fmaf(fa[e], fa[e], psum);
                qsq  = fmaf(fb[e], fb[e], qsq);
            }
            cvt8(fa, ah[kc], al[kc]);
            cvt8(fb, bh[kc], bl[kc]);
        }
        psum += __shfl_xor(psum, 16, 64);
        psum += __shfl_xor(psum, 32, 64);         // P[row il] replicated
        qsq  += __shfl_xor(qsq, 16, 64);
        qsq  += __shfl_xor(qsq, 32, 64);          // Q[col il] replicated
        float pv[4];
        #pragma unroll
        for (int r = 0; r < 4; ++r) pv[r] = __shfl(psum, 4 * g + r, 64);

        f32x4 acc = {0.f, 0.f, 0.f, 0.f};
        #pragma unroll
        for (int kc = 0; kc < 4; ++kc) {
            acc = __builtin_amdgcn_mfma_f32_16x16x32_bf16(ah[kc], bh[kc], acc, 0, 0, 0);
            acc = __builtin_amdgcn_mfma_f32_16x16x32_bf16(ah[kc], bl[kc], acc, 0, 0, 0);
            acc = __builtin_amdgcn_mfma_f32_16x16x32_bf16(al[kc], bh[kc], acc, 0, 0, 0);
        }
        const int j = j0 + jt * 16 + il;
        float cs = 0.f;
        #pragma unroll
        for (int r = 0; r < 4; ++r) {
            const int i = i0 + ih * 16 + 4 * g + r;           // always < 256
            const float rv = exp2f((pv[r] + qsq - 2.f * acc[r]) * SCALE);
            rn[(size_t)i * NJ + j] = rv;          // RAM >= 1: 0.5-threshold dead
            cs += rv;
        }
        cs += __shfl_xor(cs, 16, 64);
        cs += __shfl_xor(cs, 32, 64);
        if (l < 16) pda[((size_t)n * 17 + ib * 2 + ih) * NJ + j0 + jt * 16 + l] = cs;
    }

    // ---- row 256 (t=512): only ib==0 blocks; reuse staged Bs; full fp32.
    if (ib == 0) {
        const int jl = tid >> 3, sub = tid & 7;   // 64 j-groups x 8 lanes
        float sab = 0.f, saa = 0.f, sbb = 0.f;
        #pragma unroll
        for (int e = 0; e < 16; ++e) {
            const int c = sub * 16 + e;
            const float a = xn[c * T_LEN + 512];
            const float b = Bs[jl][c];
            sab = fmaf(a, b, sab);
            saa = fmaf(a, a, saa);
            sbb = fmaf(b, b, sbb);
        }
        #pragma unroll
        for (int o = 4; o; o >>= 1) {
            sab += __shfl_xor(sab, o, 64);
            saa += __shfl_xor(saa, o, 64);
            sbb += __shfl_xor(sbb, o, 64);
        }
        if (sub == 0) {
            const float rv = exp2f((saa + sbb - 2.f * sab) * SCALE);
            rn[(size_t)256 * NJ + j0 + jl] = rv;
            pda[((size_t)n * 17 + 16) * NJ + j0 + jl] = rv;
        }
    }
}

// ---------------- K2: w_j=rsqrt(da); per-row db + weighted rowsum; fused apply. (R12-proven)
__global__ __launch_bounds__(256) void k2(const float* __restrict__ ram,
                                          const float* __restrict__ pda,
                                          const float* __restrict__ x,
                                          float* __restrict__ out) {
    const int ic = blockIdx.x, n = blockIdx.y;
    __shared__ float w_s[NJ];
    __shared__ float f_s[16];
    const int tid = threadIdx.x;
    {
        float da = 0.f;
        #pragma unroll
        for (int k = 0; k < 17; ++k) da += pda[((size_t)n * 17 + k) * NJ + tid];
        w_s[tid] = rsqrtf(da);                    // da >= 257, eps negligible
    }
    __syncthreads();
    const int wv = tid >> 6, lane = tid & 63;
    #pragma unroll
    for (int rr = 0; rr < 4; ++rr) {
        const int lr = wv * 4 + rr;
        const int i = ic * 16 + lr;
        if (i < NI) {
            const float* rrow = ram + ((size_t)n * NI + i) * NJ;
            float db = 0.f, t0 = 0.f;
            #pragma unroll
            for (int k = 0; k < 4; ++k) {
                const float v = rrow[lane + 64 * k];
                db += v;
                t0 = fmaf(v, w_s[lane + 64 * k], t0);
            }
            #pragma unroll
            for (int off = 32; off; off >>= 1) {
                db += __shfl_xor(db, off, 64);
                t0 += __shfl_xor(t0, off, 64);
            }
            if (lane == 0) f_s[lr] = 2.f * t0 * rsqrtf(db);
        }
    }
    __syncthreads();
    const int tt = tid & 31, cgp = tid >> 5;
    const int t = ic * 32 + tt;
    if (t < T_LEN) {
        const float f = f_s[tt >> 1];
        const float* xn = x + (size_t)n * C_CH * T_LEN;
        float* on = out + (size_t)n * C_CH * T_LEN;
        #pragma unroll
        for (int p = 0; p < 16; ++p) {
            const int c = cgp * 16 + p;
            on[c * T_LEN + t] = xn[c * T_LEN + t] * f;
        }
    }
}

extern "C" void kernel_launch(void* const* d_in, const int* in_sizes, int n_in,
                              void* d_out, int out_size, void* d_ws, size_t ws_size,
                              hipStream_t stream) {
    const float* x = (const float*)d_in[0];
    float* out = (float*)d_out;
    float* ws = (float*)d_ws;
    float* ram = ws + RAM_F;
    float* pda = ws + PDA_F;

    k1<<<dim3(4, 8, N_B), 512, 0, stream>>>(x, ram, pda);
    k2<<<dim3(17, N_B), 256, 0, stream>>>(ram, pda, x, out);
}

// Round 14
// 19.346 us; speedup vs baseline: 8.3442x; 1.1085x over previous
//
#include <hip/hip_runtime.h>
#include <math.h>

#define N_B 16
#define C_CH 128
#define T_LEN 513
#define NI 257
#define NJ 256
#define NPD 9                                  // 8 i-band slots + row-256 slot
#define SCALE (1.4426950408889634f/128.0f)     // log2(e)/C

typedef unsigned u32;
typedef unsigned short u16;
typedef short bf16x8 __attribute__((ext_vector_type(8)));
typedef float f32x4 __attribute__((ext_vector_type(4)));

// workspace: RAM f32[16][257][256] ; pda f32[16][9][256]
#define RAM_F 0
#define PDA_F (N_B*NI*NJ)

__device__ inline u32 cvtpk(float a, float b) {   // packed bf16(a)|bf16(b)<<16
    u32 r;
    asm("v_cvt_pk_bf16_f32 %0, %1, %2" : "=v"(r) : "v"(a), "v"(b));
    return r;
}

// hi = rne(a,b) packed; lo = rne of exact residuals (compensates any hi rounding)
__device__ inline void cvt8(const float* fa, bf16x8& hv, bf16x8& lv) {
    union { u32 w[4]; bf16x8 v; } H, L;
    #pragma unroll
    for (int p = 0; p < 4; ++p) {
        const float a = fa[2*p], b = fa[2*p+1];
        const u32 h = cvtpk(a, b);
        const float la = a - __builtin_bit_cast(float, h << 16);
        const float lb = b - __builtin_bit_cast(float, h & 0xffff0000u);
        H.w[p] = h;
        L.w[p] = cvtpk(la, lb);
    }
    hv = H.v; lv = L.v;
}

// ---------------- K1: grid (jb=4, ib=4, n=16) = 256 blocks x 512 thr, 67.6 KB LDS.
// Block = 64 i-rows x 64 j-cols. 8 waves = (ia, jt); each wave: two 16x16 i-tiles
// sharing one B-fragment. ib==0 blocks also compute RAM row 256 (fp32 GEMV vs Bs).
__global__ __launch_bounds__(512, 2) void k1(const float* __restrict__ x,
                                             float* __restrict__ ram,
                                             float* __restrict__ pda) {
    __shared__ float As[64][132];
    __shared__ float Bs[64][132];
    const int jb = blockIdx.x, ib = blockIdx.y, n = blockIdx.z;
    const int i0 = ib * 64, j0 = jb * 64;
    const int tid = threadIdx.x;
    const int l = tid & 63, wv = tid >> 6;
    const float* xn = x + (size_t)n * (C_CH * T_LEN);
    float* rn = ram + (size_t)n * NI * NJ;

    {   // stage: wave wv covers c = 16*wv .. 16*wv+15; lane l = row index
        #pragma unroll
        for (int m = 0; m < 16; ++m) {
            const int c = wv * 16 + m;
            {   // A: even t in [2*i0, 2*i0+128)
                const int idx = c * T_LEN + 2 * i0 + 2 * l;
                const float2 f2 = *(const float2*)(xn + (idx & ~1));
                As[l][c] = (idx & 1) ? f2.y : f2.x;
            }
            {   // B: odd t in [2*j0, 2*j0+128)
                const int idx = c * T_LEN + 2 * j0 + 2 * l + 1;
                const float2 f2 = *(const float2*)(xn + (idx & ~1));
                Bs[l][c] = (idx & 1) ? f2.y : f2.x;
            }
        }
    }
    __syncthreads();

    const int il = l & 15, g = l >> 4;
    const int ia = wv >> 2, jt = wv & 3;
    {
        bf16x8 ah[2][4], al[2][4], bh[4], bl[4];
        float psum[2] = {0.f, 0.f}, qsq = 0.f;
        #pragma unroll
        for (int kc = 0; kc < 4; ++kc) {
            float fb[8];
            const float* bp = &Bs[jt * 16 + il][kc * 32 + 8 * g];
            #pragma unroll
            for (int e = 0; e < 8; ++e) fb[e] = bp[e];
            #pragma unroll
            for (int e = 0; e < 8; ++e) qsq = fmaf(fb[e], fb[e], qsq);
            cvt8(fb, bh[kc], bl[kc]);
            #pragma unroll
            for (int s = 0; s < 2; ++s) {
                float fa[8];
                const float* ap = &As[ia * 32 + s * 16 + il][kc * 32 + 8 * g];
                #pragma unroll
                for (int e = 0; e < 8; ++e) fa[e] = ap[e];
                #pragma unroll
                for (int e = 0; e < 8; ++e) psum[s] = fmaf(fa[e], fa[e], psum[s]);
                cvt8(fa, ah[s][kc], al[s][kc]);
            }
        }
        #pragma unroll
        for (int s = 0; s < 2; ++s) {
            psum[s] += __shfl_xor(psum[s], 16, 64);
            psum[s] += __shfl_xor(psum[s], 32, 64);   // P[row il] replicated
        }
        qsq += __shfl_xor(qsq, 16, 64);
        qsq += __shfl_xor(qsq, 32, 64);               // Q[col il] replicated
        float pv[2][4];
        #pragma unroll
        for (int s = 0; s < 2; ++s)
            #pragma unroll
            for (int r = 0; r < 4; ++r) pv[s][r] = __shfl(psum[s], 4 * g + r, 64);

        f32x4 acc[2];
        acc[0] = (f32x4){0.f, 0.f, 0.f, 0.f};
        acc[1] = (f32x4){0.f, 0.f, 0.f, 0.f};
        #pragma unroll
        for (int kc = 0; kc < 4; ++kc) {
            #pragma unroll
            for (int s = 0; s < 2; ++s) {
                acc[s] = __builtin_amdgcn_mfma_f32_16x16x32_bf16(ah[s][kc], bh[kc], acc[s], 0, 0, 0);
                acc[s] = __builtin_amdgcn_mfma_f32_16x16x32_bf16(ah[s][kc], bl[kc], acc[s], 0, 0, 0);
                acc[s] = __builtin_amdgcn_mfma_f32_16x16x32_bf16(al[s][kc], bh[kc], acc[s], 0, 0, 0);
            }
        }
        const int j = j0 + jt * 16 + il;
        float cs = 0.f;
        #pragma unroll
        for (int s = 0; s < 2; ++s) {
            #pragma unroll
            for (int r = 0; r < 4; ++r) {
                const int i = i0 + ia * 32 + s * 16 + 4 * g + r;   // always < 256
                const float rv = exp2f((pv[s][r] + qsq - 2.f * acc[s][r]) * SCALE);
                rn[(size_t)i * NJ + j] = rv;       // RAM >= 1: 0.5-threshold dead
                cs += rv;
            }
        }
        cs += __shfl_xor(cs, 16, 64);
        cs += __shfl_xor(cs, 32, 64);              // sum over 32 rows (this ia-half)
        if (l < 16) pda[((size_t)n * NPD + ib * 2 + ia) * NJ + j0 + jt * 16 + l] = cs;
    }

    // ---- row 256 (t=512): only ib==0 blocks; reuse staged Bs; full fp32.
    if (ib == 0) {
        const int jl = tid >> 3, sub = tid & 7;    // 64 j-rows x 8 lanes
        float sab = 0.f, saa = 0.f, sbb = 0.f;
        #pragma unroll
        for (int e = 0; e < 16; ++e) {
            const int c = sub * 16 + e;
            const float a = xn[c * T_LEN + 512];
            const float b = Bs[jl][c];
            sab = fmaf(a, b, sab);
            saa = fmaf(a, a, saa);
            sbb = fmaf(b, b, sbb);
        }
        #pragma unroll
        for (int o = 4; o; o >>= 1) {
            sab += __shfl_xor(sab, o, 64);
            saa += __shfl_xor(saa, o, 64);
            sbb += __shfl_xor(sbb, o, 64);
        }
        if (sub == 0) {
            const float rv = exp2f((saa + sbb - 2.f * sab) * SCALE);
            rn[(size_t)256 * NJ + j0 + jl] = rv;
            pda[((size_t)n * NPD + 8) * NJ + j0 + jl] = rv;
        }
    }
}

// ---------------- K2: w_j=rsqrt(da); per-row db + weighted rowsum; fused apply.
__global__ __launch_bounds__(256) void k2(const float* __restrict__ ram,
                                          const float* __restrict__ pda,
                                          const float* __restrict__ x,
                                          float* __restrict__ out) {
    const int ic = blockIdx.x, n = blockIdx.y;
    __shared__ float w_s[NJ];
    __shared__ float f_s[16];
    const int tid = threadIdx.x;
    {
        float da = 0.f;
        #pragma unroll
        for (int k = 0; k < NPD; ++k) da += pda[((size_t)n * NPD + k) * NJ + tid];
        w_s[tid] = rsqrtf(da);                    // da >= 257, eps negligible
    }
    __syncthreads();
    const int wv = tid >> 6, lane = tid & 63;
    #pragma unroll
    for (int rr = 0; rr < 4; ++rr) {
        const int lr = wv * 4 + rr;
        const int i = ic * 16 + lr;
        if (i < NI) {
            const float* rrow = ram + ((size_t)n * NI + i) * NJ;
            float db = 0.f, t0 = 0.f;
            #pragma unroll
            for (int k = 0; k < 4; ++k) {
                const float v = rrow[lane + 64 * k];
                db += v;
                t0 = fmaf(v, w_s[lane + 64 * k], t0);
            }
            #pragma unroll
            for (int off = 32; off; off >>= 1) {
                db += __shfl_xor(db, off, 64);
                t0 += __shfl_xor(t0, off, 64);
            }
            if (lane == 0) f_s[lr] = 2.f * t0 * rsqrtf(db);
        }
    }
    __syncthreads();
    const int tt = tid & 31, cgp = tid >> 5;
    const int t = ic * 32 + tt;
    if (t < T_LEN) {
        const float f = f_s[tt >> 1];
        const float* xn = x + (size_t)n * C_CH * T_LEN;
        float* on = out + (size_t)n * C_CH * T_LEN;
        #pragma unroll
        for (int p = 0; p < 16; ++p) {
            const int c = cgp * 16 + p;
            on[c * T_LEN + t] = xn[c * T_LEN + t] * f;
        }
    }
}

extern "C" void kernel_launch(void* const* d_in, const int* in_sizes, int n_in,
                              void* d_out, int out_size, void* d_ws, size_t ws_size,
                              hipStream_t stream) {
    const float* x = (const float*)d_in[0];
    float* out = (float*)d_out;
    float* ws = (float*)d_ws;
    float* ram = ws + RAM_F;
    float* pda = ws + PDA_F;

    k1<<<dim3(4, 4, N_B), 512, 0, stream>>>(x, ram, pda);
    k2<<<dim3(17, N_B), 256, 0, stream>>>(ram, pda, x, out);
}

// Round 15
// 19.257 us; speedup vs baseline: 8.3826x; 1.0046x over previous
//
#include <hip/hip_runtime.h>
#include <math.h>

#define N_B 16
#define C_CH 128
#define T_LEN 513
#define NI 257
#define NJ 256
#define NPD 9                                  // 8 i-band slots + row-256 slot
#define SCALE (1.4426950408889634f/128.0f)     // log2(e)/C

typedef unsigned u32;
typedef unsigned short u16;
typedef short bf16x8 __attribute__((ext_vector_type(8)));
typedef float f32x4 __attribute__((ext_vector_type(4)));
typedef u32 u32x4 __attribute__((ext_vector_type(4)));

// workspace: RAM f32[16][257][256] ; pda f32[16][9][256]
#define RAM_F 0
#define PDA_F (N_B*NI*NJ)

__device__ inline u32 cvtpk(float a, float b) {   // dst = bf16(a) | bf16(b)<<16
    u32 r;
    asm("v_cvt_pk_bf16_f32 %0, %1, %2" : "=v"(r) : "v"(a), "v"(b));
    return r;
}

// ---------------- K1: grid (jb=4, ib=4, n=16) = 256 blocks x 512 thr.
// Block = 64 i x 64 j. Staging converts to bf16 hi/lo LDS planes ONCE per value
// (cvt redundancy 4x/2x -> 1x); compute phase reads fragments directly (b128).
// P/Q computed exactly in fp32 at staging. ib==0 blocks also do row 256.
__global__ __launch_bounds__(512, 2) void k1(const float* __restrict__ x,
                                             float* __restrict__ ram,
                                             float* __restrict__ pda) {
    __shared__ u16 Ah[64][136], Al[64][136], Bh[64][136], Bl[64][136];
    __shared__ float PpT[8][64], QpT[8][64];
    __shared__ float Ps[64], Qs[64];
    const int jb = blockIdx.x, ib = blockIdx.y, n = blockIdx.z;
    const int i0 = ib * 64, j0 = jb * 64;
    const int tid = threadIdx.x;
    const int l = tid & 63, wv = tid >> 6;
    const float* xn = x + (size_t)n * (C_CH * T_LEN);
    float* rn = ram + (size_t)n * NI * NJ;

    // ---- staging: thread (wv,l) owns LDS row l, c = 16*wv .. 16*wv+15
    {
        float av[16], bv[16];
        #pragma unroll
        for (int m = 0; m < 16; ++m) {
            const int c = wv * 16 + m;
            {   // A: even t in [2*i0, 2*i0+128)
                const int idx = c * T_LEN + 2 * i0 + 2 * l;
                const float2 f2 = *(const float2*)(xn + (idx & ~1));
                av[m] = (idx & 1) ? f2.y : f2.x;
            }
            {   // B: odd t in [2*j0, 2*j0+128)
                const int idx = c * T_LEN + 2 * j0 + 2 * l + 1;
                const float2 f2 = *(const float2*)(xn + (idx & ~1));
                bv[m] = (idx & 1) ? f2.y : f2.x;
            }
        }
        float pp = 0.f, qq = 0.f;
        u32 ahw[8], alw[8], bhw[8], blw[8];
        #pragma unroll
        for (int p = 0; p < 8; ++p) {
            const float a0 = av[2*p], a1 = av[2*p+1];
            const float b0 = bv[2*p], b1 = bv[2*p+1];
            pp = fmaf(a0, a0, fmaf(a1, a1, pp));
            qq = fmaf(b0, b0, fmaf(b1, b1, qq));
            const u32 ha = cvtpk(a0, a1);
            ahw[p] = ha;
            alw[p] = cvtpk(a0 - __builtin_bit_cast(float, ha << 16),
                           a1 - __builtin_bit_cast(float, ha & 0xffff0000u));
            const u32 hb = cvtpk(b0, b1);
            bhw[p] = hb;
            blw[p] = cvtpk(b0 - __builtin_bit_cast(float, hb << 16),
                           b1 - __builtin_bit_cast(float, hb & 0xffff0000u));
        }
        u32* d;
        d = (u32*)&Ah[l][16 * wv]; *(u32x4*)d = *(u32x4*)&ahw[0]; *(u32x4*)(d + 4) = *(u32x4*)&ahw[4];
        d = (u32*)&Al[l][16 * wv]; *(u32x4*)d = *(u32x4*)&alw[0]; *(u32x4*)(d + 4) = *(u32x4*)&alw[4];
        d = (u32*)&Bh[l][16 * wv]; *(u32x4*)d = *(u32x4*)&bhw[0]; *(u32x4*)(d + 4) = *(u32x4*)&bhw[4];
        d = (u32*)&Bl[l][16 * wv]; *(u32x4*)d = *(u32x4*)&blw[0]; *(u32x4*)(d + 4) = *(u32x4*)&blw[4];
        PpT[wv][l] = pp;
        QpT[wv][l] = qq;
    }
    __syncthreads();

    // P/Q reduction (exact fp32, fixed order); overlaps with frag reads below
    if (tid < 64) {
        float s = 0.f;
        #pragma unroll
        for (int w = 0; w < 8; ++w) s += PpT[w][tid];
        Ps[tid] = s;
    } else if (tid < 128) {
        float s = 0.f;
        #pragma unroll
        for (int w = 0; w < 8; ++w) s += QpT[w][tid - 64];
        Qs[tid - 64] = s;
    }

    const int il = l & 15, g = l >> 4;
    const int ia = wv >> 2, jt = wv & 3;
    bf16x8 fah[2][4], fal[2][4], fbh[4], fbl[4];
    #pragma unroll
    for (int kc = 0; kc < 4; ++kc) {
        fbh[kc]    = *(const bf16x8*)&Bh[jt * 16 + il][kc * 32 + 8 * g];
        fbl[kc]    = *(const bf16x8*)&Bl[jt * 16 + il][kc * 32 + 8 * g];
        fah[0][kc] = *(const bf16x8*)&Ah[ia * 32 + il][kc * 32 + 8 * g];
        fah[1][kc] = *(const bf16x8*)&Ah[ia * 32 + 16 + il][kc * 32 + 8 * g];
        fal[0][kc] = *(const bf16x8*)&Al[ia * 32 + il][kc * 32 + 8 * g];
        fal[1][kc] = *(const bf16x8*)&Al[ia * 32 + 16 + il][kc * 32 + 8 * g];
    }
    f32x4 acc[2];
    acc[0] = (f32x4){0.f, 0.f, 0.f, 0.f};
    acc[1] = (f32x4){0.f, 0.f, 0.f, 0.f};
    #pragma unroll
    for (int kc = 0; kc < 4; ++kc) {
        #pragma unroll
        for (int s = 0; s < 2; ++s) {
            acc[s] = __builtin_amdgcn_mfma_f32_16x16x32_bf16(fah[s][kc], fbh[kc], acc[s], 0, 0, 0);
            acc[s] = __builtin_amdgcn_mfma_f32_16x16x32_bf16(fah[s][kc], fbl[kc], acc[s], 0, 0, 0);
            acc[s] = __builtin_amdgcn_mfma_f32_16x16x32_bf16(fal[s][kc], fbh[kc], acc[s], 0, 0, 0);
        }
    }
    __syncthreads();                              // Ps/Qs now visible

    const float qv = Qs[jt * 16 + il];
    const int j = j0 + jt * 16 + il;
    float cs = 0.f;
    #pragma unroll
    for (int s = 0; s < 2; ++s) {
        #pragma unroll
        for (int r = 0; r < 4; ++r) {
            const int iloc = ia * 32 + s * 16 + 4 * g + r;
            const float rv = exp2f((Ps[iloc] + qv - 2.f * acc[s][r]) * SCALE);
            rn[(size_t)(i0 + iloc) * NJ + j] = rv;   // RAM >= 1: 0.5-threshold dead
            cs += rv;
        }
    }
    cs += __shfl_xor(cs, 16, 64);
    cs += __shfl_xor(cs, 32, 64);                 // sum over this ia-half's 32 rows
    if (l < 16) pda[((size_t)n * NPD + ib * 2 + ia) * NJ + j0 + jt * 16 + l] = cs;

    // ---- row 256 (t=512): ib==0 blocks; b reconstructed from hi+lo (2^-18 rel)
    if (ib == 0) {
        const int jl = tid >> 3, sub = tid & 7;   // 64 j-rows x 8 lanes
        float sab = 0.f, saa = 0.f, sbb = 0.f;
        #pragma unroll
        for (int e = 0; e < 16; ++e) {
            const int c = sub * 16 + e;
            const float a = xn[c * T_LEN + 512];
            const float b = __builtin_bit_cast(float, (u32)Bh[jl][c] << 16)
                          + __builtin_bit_cast(float, (u32)Bl[jl][c] << 16);
            sab = fmaf(a, b, sab);
            saa = fmaf(a, a, saa);
            sbb = fmaf(b, b, sbb);
        }
        #pragma unroll
        for (int o = 4; o; o >>= 1) {
            sab += __shfl_xor(sab, o, 64);
            saa += __shfl_xor(saa, o, 64);
            sbb += __shfl_xor(sbb, o, 64);
        }
        if (sub == 0) {
            const float rv = exp2f((saa + sbb - 2.f * sab) * SCALE);
            rn[(size_t)256 * NJ + j0 + jl] = rv;
            pda[((size_t)n * NPD + 8) * NJ + j0 + jl] = rv;
        }
    }
}

// ---------------- K2: w_j=rsqrt(da); per-row db + weighted rowsum; fused apply. (proven)
__global__ __launch_bounds__(256) void k2(const float* __restrict__ ram,
                                          const float* __restrict__ pda,
                                          const float* __restrict__ x,
                                          float* __restrict__ out) {
    const int ic = blockIdx.x, n = blockIdx.y;
    __shared__ float w_s[NJ];
    __shared__ float f_s[16];
    const int tid = threadIdx.x;
    {
        float da = 0.f;
        #pragma unroll
        for (int k = 0; k < NPD; ++k) da += pda[((size_t)n * NPD + k) * NJ + tid];
        w_s[tid] = rsqrtf(da);                    // da >= 257, eps negligible
    }
    __syncthreads();
    const int wv = tid >> 6, lane = tid & 63;
    #pragma unroll
    for (int rr = 0; rr < 4; ++rr) {
        const int lr = wv * 4 + rr;
        const int i = ic * 16 + lr;
        if (i < NI) {
            const float* rrow = ram + ((size_t)n * NI + i) * NJ;
            float db = 0.f, t0 = 0.f;
            #pragma unroll
            for (int k = 0; k < 4; ++k) {
                const float v = rrow[lane + 64 * k];
                db += v;
                t0 = fmaf(v, w_s[lane + 64 * k], t0);
            }
            #pragma unroll
            for (int off = 32; off; off >>= 1) {
                db += __shfl_xor(db, off, 64);
                t0 += __shfl_xor(t0, off, 64);
            }
            if (lane == 0) f_s[lr] = 2.f * t0 * rsqrtf(db);
        }
    }
    __syncthreads();
    const int tt = tid & 31, cgp = tid >> 5;
    const int t = ic * 32 + tt;
    if (t < T_LEN) {
        const float f = f_s[tt >> 1];
        const float* xn = x + (size_t)n * C_CH * T_LEN;
        float* on = out + (size_t)n * C_CH * T_LEN;
        #pragma unroll
        for (int p = 0; p < 16; ++p) {
            const int c = cgp * 16 + p;
            on[c * T_LEN + t] = xn[c * T_LEN + t] * f;
        }
    }
}

extern "C" void kernel_launch(void* const* d_in, const int* in_sizes, int n_in,
                              void* d_out, int out_size, void* d_ws, size_t ws_size,
                              hipStream_t stream) {
    const float* x = (const float*)d_in[0];
    float* out = (float*)d_out;
    float* ws = (float*)d_ws;
    float* ram = ws + RAM_F;
    float* pda = ws + PDA_F;

    k1<<<dim3(4, 4, N_B), 512, 0, stream>>>(x, ram, pda);
    k2<<<dim3(17, N_B), 256, 0, stream>>>(ram, pda, x, out);
}